// Round 1
// baseline (440.665 us; speedup 1.0000x reference)
//
#include <hip/hip_runtime.h>

#define MU_C     0.5f
#define C_NORM_C 8.0f
#define CG_IT    10
#define LRELU_C  0.2f
#define EPS_C    1e-12f

constexpr int BB = 16;   // batch
constexpr int KK = 16;   // neighbors
constexpr int FF = 3;    // features
constexpr int EE = 6;    // embedding dim

// ws scalar slots (floats):
// sc[0]      : norm accumulator (sum deg^2 + sum w^2)
// sc[1]      : musc = MU * C / sqrt(sc[0])
// sc[2..17]  : rs0[b]
// sc[32+16i ..]  : pAp slot for iter i
// sc[192+16i ..] : rs_new slot for iter i

__global__ void k_zero_scalars(float* sc) {
    sc[threadIdx.x] = 0.0f;
}

__global__ void k_feat(const float* __restrict__ x,
                       const float* __restrict__ emb,
                       const float* __restrict__ fcw,
                       const float* __restrict__ fcb,
                       float* __restrict__ ff,
                       int N) {
    int n = blockIdx.x * blockDim.x + threadIdx.x;
    if (n >= N) return;
    float ev[EE];
#pragma unroll
    for (int j = 0; j < EE; ++j) ev[j] = emb[(size_t)n * EE + j];
    float g[FF], w0[FF];
#pragma unroll
    for (int f = 0; f < FF; ++f) {
        w0[f] = fcw[f * (EE + 1)];
        float s = fcb[f];
#pragma unroll
        for (int j = 0; j < EE; ++j) s += fcw[f * (EE + 1) + 1 + j] * ev[j];
        g[f] = s;
    }
    float o[BB * FF];
#pragma unroll
    for (int b = 0; b < BB; ++b) {
        float xv = x[(size_t)b * N + n];
#pragma unroll
        for (int f = 0; f < FF; ++f) {
            float v = g[f] + w0[f] * xv;
            o[b * FF + f] = (v >= 0.f) ? v : LRELU_C * v;
        }
    }
    float4* dst = (float4*)(ff + (size_t)n * (BB * FF));
#pragma unroll
    for (int q = 0; q < (BB * FF) / 4; ++q) dst[q] = ((const float4*)o)[q];
}

__global__ void k_weights(const int* __restrict__ nl,
                          const float* __restrict__ ff,
                          const float* __restrict__ theta_p,
                          float* __restrict__ w,
                          float* __restrict__ sc,
                          int N) {
    __shared__ float lds[8];
    int n = blockIdx.x * blockDim.x + threadIdx.x;
    float tp = 0.f;
    if (n < N) {
        float inv2t = 0.5f / theta_p[0];
        float fs[BB * FF];
        const float4* src = (const float4*)(ff + (size_t)n * 48);
#pragma unroll
        for (int q = 0; q < 12; ++q) ((float4*)fs)[q] = src[q];
        int idx[KK];
        const int4* isrc = (const int4*)(nl + (size_t)n * KK);
#pragma unroll
        for (int q = 0; q < 4; ++q) ((int4*)idx)[q] = isrc[q];
        float deg = 0.f, sw2 = 0.f;
#pragma unroll
        for (int k = 0; k < KK; ++k) {
            int nbr = idx[k];
            float m = (nbr >= 0) ? 1.f : 0.f;
            int nbs = nbr < 0 ? 0 : nbr;
            float fn[BB * FF];
            const float4* ns = (const float4*)(ff + (size_t)nbs * 48);
#pragma unroll
            for (int q = 0; q < 12; ++q) ((float4*)fn)[q] = ns[q];
            float s = 0.f;
#pragma unroll
            for (int b = 0; b < BB; ++b) {
                float d0 = fs[b * 3 + 0] - fn[b * 3 + 0];
                float d1 = fs[b * 3 + 1] - fn[b * 3 + 1];
                float d2 = fs[b * 3 + 2] - fn[b * 3 + 2];
                s += __expf(-(d0 * d0 + d1 * d1 + d2 * d2) * inv2t);
            }
            float wk = s * (1.f / BB) * m;
            w[(size_t)n * KK + k] = wk;
            deg += wk;
            sw2 += wk * wk;
        }
        tp = deg * deg + sw2;
    }
#pragma unroll
    for (int off = 32; off > 0; off >>= 1) tp += __shfl_down(tp, off);
    int lane = threadIdx.x & 63, wid = threadIdx.x >> 6;
    if (lane == 0) lds[wid] = tp;
    __syncthreads();
    if (threadIdx.x == 0) {
        float s = 0.f;
        int nw = blockDim.x >> 6;
        for (int wv = 0; wv < nw; ++wv) s += lds[wv];
        atomicAdd(sc, s);
    }
}

__global__ void k_scale(float* sc) {
    if (threadIdx.x == 0) {
        sc[1] = MU_C * C_NORM_C / sqrtf(sc[0]);
    }
}

// helper macro-free 16-wide (4 per thread over stride-4 lanes) block reduce + atomic
__device__ __forceinline__ void reduce_q4_atomic(float part[4], float* lds, float* target) {
#pragma unroll
    for (int j = 0; j < 4; ++j) {
#pragma unroll
        for (int off = 32; off >= 4; off >>= 1) part[j] += __shfl_down(part[j], off);
    }
    int lane = threadIdx.x & 63, wid = threadIdx.x >> 6;
    if (lane < 4) {
#pragma unroll
        for (int j = 0; j < 4; ++j) lds[wid * 16 + lane * 4 + j] = part[j];
    }
    __syncthreads();
    if (threadIdx.x < 16) {
        float s = 0.f;
        int nw = blockDim.x >> 6;
        for (int wv = 0; wv < nw; ++wv) s += lds[wv * 16 + threadIdx.x];
        atomicAdd(target + threadIdx.x, s);
    }
}

__global__ void k_cg_init(const float* __restrict__ x,
                          float* __restrict__ p,
                          float* __restrict__ r,
                          float* __restrict__ xk,
                          float* __restrict__ rs0,
                          int N) {
    __shared__ float lds[64];
    int t = blockIdx.x * blockDim.x + threadIdx.x;
    float part[4] = {0.f, 0.f, 0.f, 0.f};
    if (t < N * 4) {
        int n = t >> 2, q = t & 3;
        float v0 = x[(size_t)(q * 4 + 0) * N + n];
        float v1 = x[(size_t)(q * 4 + 1) * N + n];
        float v2 = x[(size_t)(q * 4 + 2) * N + n];
        float v3 = x[(size_t)(q * 4 + 3) * N + n];
        part[0] = v0 * v0; part[1] = v1 * v1; part[2] = v2 * v2; part[3] = v3 * v3;
        float4 vv = make_float4(v0, v1, v2, v3);
        *(float4*)(p + (size_t)n * 16 + q * 4) = vv;
        *(float4*)(r + (size_t)n * 16 + q * 4) = vv;
        *(float4*)(xk + (size_t)n * 16 + q * 4) = make_float4(0.f, 0.f, 0.f, 0.f);
    }
    reduce_q4_atomic(part, lds, rs0);
}

__global__ void k_apply(const float* __restrict__ w,
                        const int* __restrict__ nl,
                        const float* __restrict__ p,
                        float* __restrict__ Ap,
                        const float* __restrict__ sc,
                        float* __restrict__ pAp_slot,
                        int N) {
    __shared__ float lds[64];
    int t = blockIdx.x * blockDim.x + threadIdx.x;
    float part[4] = {0.f, 0.f, 0.f, 0.f};
    if (t < N * 4) {
        int n = t >> 2, q = t & 3;
        float musc = sc[1];
        float4 pq = *(const float4*)(p + (size_t)n * 16 + q * 4);
        int idx[KK];
#pragma unroll
        for (int qq = 0; qq < 4; ++qq)
            ((int4*)idx)[qq] = ((const int4*)(nl + (size_t)n * KK))[qq];
        float wr[KK];
#pragma unroll
        for (int qq = 0; qq < 4; ++qq)
            ((float4*)wr)[qq] = ((const float4*)(w + (size_t)n * KK))[qq];
        float a0 = 0.f, a1 = 0.f, a2 = 0.f, a3 = 0.f;
#pragma unroll
        for (int k = 0; k < KK; ++k) {
            int nb = idx[k] < 0 ? 0 : idx[k];
            float4 pn = *(const float4*)(p + (size_t)nb * 16 + q * 4);
            float wk = wr[k];
            a0 += wk * (pq.x - pn.x);
            a1 += wk * (pq.y - pn.y);
            a2 += wk * (pq.z - pn.z);
            a3 += wk * (pq.w - pn.w);
        }
        float4 ap;
        ap.x = pq.x + musc * a0;
        ap.y = pq.y + musc * a1;
        ap.z = pq.z + musc * a2;
        ap.w = pq.w + musc * a3;
        *(float4*)(Ap + (size_t)n * 16 + q * 4) = ap;
        part[0] = pq.x * ap.x; part[1] = pq.y * ap.y;
        part[2] = pq.z * ap.z; part[3] = pq.w * ap.w;
    }
    reduce_q4_atomic(part, lds, pAp_slot);
}

__global__ void k_update1(const float* __restrict__ rs_prev,
                          const float* __restrict__ pAp_slot,
                          const float* __restrict__ p,
                          const float* __restrict__ Ap,
                          float* __restrict__ xk,
                          float* __restrict__ r,
                          float* __restrict__ rsn_slot,
                          int N) {
    __shared__ float lds[64];
    int t = blockIdx.x * blockDim.x + threadIdx.x;
    float part[4] = {0.f, 0.f, 0.f, 0.f};
    if (t < N * 4) {
        int n = t >> 2, q = t & 3;
        float al0 = rs_prev[q * 4 + 0] / (pAp_slot[q * 4 + 0] + EPS_C);
        float al1 = rs_prev[q * 4 + 1] / (pAp_slot[q * 4 + 1] + EPS_C);
        float al2 = rs_prev[q * 4 + 2] / (pAp_slot[q * 4 + 2] + EPS_C);
        float al3 = rs_prev[q * 4 + 3] / (pAp_slot[q * 4 + 3] + EPS_C);
        size_t o = (size_t)n * 16 + q * 4;
        float4 pq  = *(const float4*)(p + o);
        float4 apq = *(const float4*)(Ap + o);
        float4 xq  = *(float4*)(xk + o);
        float4 rq  = *(float4*)(r + o);
        xq.x += al0 * pq.x; xq.y += al1 * pq.y; xq.z += al2 * pq.z; xq.w += al3 * pq.w;
        rq.x -= al0 * apq.x; rq.y -= al1 * apq.y; rq.z -= al2 * apq.z; rq.w -= al3 * apq.w;
        *(float4*)(xk + o) = xq;
        *(float4*)(r + o) = rq;
        part[0] = rq.x * rq.x; part[1] = rq.y * rq.y;
        part[2] = rq.z * rq.z; part[3] = rq.w * rq.w;
    }
    reduce_q4_atomic(part, lds, rsn_slot);
}

__global__ void k_update2(const float* __restrict__ rs_prev,
                          const float* __restrict__ rsn_slot,
                          const float* __restrict__ r,
                          float* __restrict__ p,
                          int N) {
    int t = blockIdx.x * blockDim.x + threadIdx.x;
    if (t >= N * 4) return;
    int n = t >> 2, q = t & 3;
    float b0 = rsn_slot[q * 4 + 0] / (rs_prev[q * 4 + 0] + EPS_C);
    float b1 = rsn_slot[q * 4 + 1] / (rs_prev[q * 4 + 1] + EPS_C);
    float b2 = rsn_slot[q * 4 + 2] / (rs_prev[q * 4 + 2] + EPS_C);
    float b3 = rsn_slot[q * 4 + 3] / (rs_prev[q * 4 + 3] + EPS_C);
    size_t o = (size_t)n * 16 + q * 4;
    float4 rq = *(const float4*)(r + o);
    float4 pq = *(float4*)(p + o);
    pq.x = rq.x + b0 * pq.x;
    pq.y = rq.y + b1 * pq.y;
    pq.z = rq.z + b2 * pq.z;
    pq.w = rq.w + b3 * pq.w;
    *(float4*)(p + o) = pq;
}

__global__ void k_out(const float* __restrict__ xk, float* __restrict__ out, int N) {
    int t = blockIdx.x * blockDim.x + threadIdx.x;
    if (t >= N * 4) return;
    int n = t >> 2, q = t & 3;
    float4 v = *(const float4*)(xk + (size_t)n * 16 + q * 4);
    out[(size_t)(q * 4 + 0) * N + n] = v.x;
    out[(size_t)(q * 4 + 1) * N + n] = v.y;
    out[(size_t)(q * 4 + 2) * N + n] = v.z;
    out[(size_t)(q * 4 + 3) * N + n] = v.w;
}

extern "C" void kernel_launch(void* const* d_in, const int* in_sizes, int n_in,
                              void* d_out, int out_size, void* d_ws, size_t ws_size,
                              hipStream_t stream) {
    const float* x   = (const float*)d_in[0];
    const int*   nl  = (const int*)d_in[1];
    const float* emb = (const float*)d_in[2];
    const float* fcw = (const float*)d_in[3];
    const float* fcb = (const float*)d_in[4];
    const float* th  = (const float*)d_in[5];
    int N = in_sizes[1] / KK;   // 50000

    float* sc  = (float*)d_ws;                 // 512 floats of scalar slots
    float* w   = sc + 512;                     // N*KK
    float* reg = w + (size_t)N * KK;           // reused region
    float* ff  = reg;                          // N*48 (phase 1 only)
    float* p   = reg;                          // N*16 (aliases ff, after k_weights)
    float* r   = reg + (size_t)N * 16;
    float* xk  = reg + (size_t)N * 32;
    float* Ap  = reg + (size_t)N * 48;
    float* rs0 = sc + 2;

    int G1 = (N + 255) / 256;
    int G4 = (N * 4 + 255) / 256;

    k_zero_scalars<<<1, 512, 0, stream>>>(sc);
    k_feat<<<G1, 256, 0, stream>>>(x, emb, fcw, fcb, ff, N);
    k_weights<<<G1, 256, 0, stream>>>(nl, ff, th, w, sc, N);
    k_scale<<<1, 64, 0, stream>>>(sc);
    k_cg_init<<<G4, 256, 0, stream>>>(x, p, r, xk, rs0, N);

    const float* rsp = rs0;
    for (int i = 0; i < CG_IT; ++i) {
        float* pap = sc + 32 + 16 * i;
        float* rsn = sc + 192 + 16 * i;
        k_apply<<<G4, 256, 0, stream>>>(w, nl, p, Ap, sc, pap, N);
        k_update1<<<G4, 256, 0, stream>>>(rsp, pap, p, Ap, xk, r, rsn, N);
        if (i + 1 < CG_IT)
            k_update2<<<G4, 256, 0, stream>>>(rsp, rsn, r, p, N);
        rsp = rsn;
    }
    k_out<<<G4, 256, 0, stream>>>(xk, (float*)d_out, N);
}